// Round 15
// baseline (365.203 us; speedup 1.0000x reference)
//
#include <hip/hip_runtime.h>
#include <math.h>

// ---------------------------------------------------------------------------
// Sinkhorn ETP (FASTopic) on MI355X.
// n=256 topics, m=32768 words, D=384.
//
//   log_K0[i,j] = G[i,j] + su0[i] + sv0[j],  G = 40 * x@y^T
//   Per iteration:  W[j] = log_b - lse_i(G+su);  su'[i] = log_a - lse_j(G+W)
//   Final: transp[i,j] = exp(G+su[i]+W[j]); M = nx[i]+ny[j]-0.05*G;
//          loss = sum(transp*M)
//
// R16 (308) / R22 (307.6, validated model): persistent loop = 75us G
// cold-load + 93us loop (1.8us/iter) + 13us fused finalize; gemm ~50 + init
// ~15 separate. ~85us is pure G memory transit (gemm store + boundary load).
// R17-R20 fusion failures all reduce to ONE constraint: per-thread register
// peak (acc[4][8]+tile[32] = 256+ live -> spill; fragment-layout loop slow;
// in-kernel memory exchange missed L2 under y-streaming).
//
// R23: gemm fused INSIDE the persistent kernel, exchanged via LDS in
// register-safe slices. Four 32-col passes: acc[4][2] (32 regs) per pass;
// after each pass, fragments -> iteration layout through a 9KB LDS chunk
// buffer. Thread's 4 iteration cols = jq+{0,32,64,96} (one per pass) so
// tile[32] fills ONE float4 component per pass, uniformly: peak = tile 96 +
// acc 32 + frags ~50 = 182 = R22's proven budget. Exchange also dribbles G
// to memory (L2-local, coalesced) so Phase D stays R22-verbatim (reload;
// avoids R21's tile-into-tail spill). MFMA 6-term order + kc order identical
// to gemm_k -> G bitwise identical. gemm_k + the 75us boundary load DELETED.
// Predicted: fused_k 150-185us (A ~50-65, loop 93, D 13), VGPR 185-215,
// WRITE ~78MB, FETCH ~50MB; total ~190-220. Falsifiers: absmax -> mapping
// bug; WRITE>>95MB -> spill -> R22 is plateau; fused>230 -> staging cost.
// ---------------------------------------------------------------------------

#define N_TOPIC 256
#define N_WORD  32768

static constexpr float LOG_A = -5.545177444479562f;    // log(1/256 + 1e-30)
static constexpr float LOG_B = -10.397207708399179f;   // log(1/32768 + 1e-30)
static constexpr float BVAL  = 3.0517578125e-05f;      // 1/32768

typedef float f32x4 __attribute__((ext_vector_type(4)));
typedef short bf16x8 __attribute__((ext_vector_type(8)));

// Keep a float4's lanes pinned in VGPRs (opaque use+def; no remat).
#define PIN4(v) asm volatile("" : "+v"((v).x), "+v"((v).y), "+v"((v).z), "+v"((v).w))

// ---------------------------------------------------------------- init ------
__global__ __launch_bounds__(256) void init_k(
    const float* __restrict__ x, const float* __restrict__ y,
    float* __restrict__ nx, float* __restrict__ ny, float* __restrict__ su,
    unsigned* __restrict__ colerr, int* __restrict__ active,
    int* __restrict__ counters, float* __restrict__ out)
{
    const int b = blockIdx.x, t = threadIdx.x;
    const int w = t >> 6, l = t & 63;
    if (b < 8192) {                       // ||y_j||^2, 4 rows/block (wave per row)
        const int r = (b << 2) + w;
        const float4* y4 = (const float4*)y;
        float4 v = y4[r * 96 + l];
        float s = v.x * v.x + v.y * v.y + v.z * v.z + v.w * v.w;
        if (l < 32) {
            float4 u = y4[r * 96 + 64 + l];
            s += u.x * u.x + u.y * u.y + u.z * u.z + u.w * u.w;
        }
        for (int off = 32; off; off >>= 1) s += __shfl_down(s, off);
        if (l == 0) ny[r] = s;
    } else if (b < 8256) {                // ||x_i||^2 and su0 = -20*nx
        const int r = ((b - 8192) << 2) + w;
        const float4* x4 = (const float4*)x;
        float4 v = x4[r * 96 + l];
        float s = v.x * v.x + v.y * v.y + v.z * v.z + v.w * v.w;
        if (l < 32) {
            float4 u = x4[r * 96 + 64 + l];
            s += u.x * u.x + u.y * u.y + u.z * u.z + u.w * u.w;
        }
        for (int off = 32; off; off >>= 1) s += __shfl_down(s, off);
        if (l == 0) { nx[r] = s; su[r] = -20.f * s; }
    } else {
        for (int k = t; k < 4096; k += 256) counters[k] = 0;
        if (t == 0) { colerr[0] = 0u; colerr[1] = 0u; active[0] = 1; out[0] = 0.f; }
    }
}

// Exact 3-way bf16 truncation split: v = b0 + b1 + b2 (+ r3, |r3|<=2^-27|v|).
static __device__ __forceinline__ void split3(float v, ushort& h0, ushort& h1, ushort& h2)
{
    unsigned u0 = __float_as_uint(v);
    h0 = (ushort)(u0 >> 16);
    float r1 = v - __uint_as_float(u0 & 0xFFFF0000u);
    unsigned u1 = __float_as_uint(r1);
    h1 = (ushort)(u1 >> 16);
    float r2 = r1 - __uint_as_float(u1 & 0xFFFF0000u);
    h2 = (ushort)(__float_as_uint(r2) >> 16);
}

// ----------------------------------------------- persistent barrier ---------
static __device__ __forceinline__ bool bar_arrive(int* cnt, int ph, int t, int* lastf)
{
    __threadfence();
    if (t == 0) *lastf = (atomicAdd(&cnt[ph], 1) == 255);
    __syncthreads();
    return *lastf != 0;
}
static __device__ __forceinline__ void bar_release(int* gen, int ph, int t)
{
    __threadfence();
    if (t == 0) atomicExch(gen, ph);
}
static __device__ __forceinline__ void bar_wait(int* gen, int ph, int t)
{
    if (t == 0) {
        while (atomicCAS(gen, -1, -1) < ph) __builtin_amdgcn_s_sleep(2);
    }
    __syncthreads();
    __threadfence();
}

// ------------------- fused gemm + Sinkhorn loop + finalize -------------------
// 256 blocks x 256 threads, 1 block/CU. Block b owns cols [128b,128b+128).
// Phase A (x4 passes, PP=0..3): MFMA 256x32 sub-tile (acc[4][2]) for local
//   cols [32PP,32PP+32); exchange via exb to tile[k] component PP (thread's
//   iteration cols = jq+{0,32,64,96}); dribble chunk to G (L2-local).
// Loop: R22 structure with per-component col indexing. Phase D: R22 verbatim
//   (reload G; tile dead at loop exit).
__global__ __launch_bounds__(256, 1) void fused_k(
    const float* __restrict__ x, const float* __restrict__ y,
    float* __restrict__ G, float* __restrict__ su,
    const float* __restrict__ nx, const float* __restrict__ ny,
    float2* __restrict__ pms, float* __restrict__ prow,
    int* __restrict__ cnt, int* __restrict__ gen,
    unsigned* __restrict__ colerr, int* __restrict__ active,
    float* __restrict__ out)
{
    __shared__ __align__(16) char smem[56832];
    __shared__ int lastf;
    // Phase-A staging region (time-disjoint with iteration region)
    float4* xs4 = (float4*)smem;                  // [256][8] float4 = 32768 B
    ushort* ys0 = (ushort*)(smem + 32768);        // [32][40] = 2560 B
    ushort* ys1 = (ushort*)(smem + 35328);
    ushort* ys2 = (ushort*)(smem + 37888);        // ends 40448
    float*  exb = (float*)(smem + 47616);         // [64][36] = 9216 B -> 56832
    // iteration/finalize region
    float* su_lds = (float*)smem;                 // 256f
    float* mm    = (float*)(smem + 1024);         // [8][128]
    float* ss    = (float*)(smem + 5120);         // [8][128]
    float* Mcol  = (float*)(smem + 9216);         // 128f
    float* Wlds  = (float*)(smem + 9728);         // 128f
    float* ecol  = (float*)(smem + 10240);        // 128f
    float* Rlds  = (float*)(smem + 10752);        // 256f
    float* errb  = (float*)(smem + 11776);        // 128f
    float* nxl   = (float*)(smem + 12288);        // 256f
    float* nyl   = (float*)(smem + 13312);        // 128f
    float* pq    = (float*)(smem + 13824);        // [256][33] -> ends 47616

    const int t  = threadIdx.x;
    const int b  = blockIdx.x;
    const int w  = t >> 6, ln = t & 63, q = ln >> 4, l15 = ln & 15;
    const int jq = t & 31, ig = t >> 5;
    const int c0 = jq << 2;              // Phase-D col quad (R22 mapping)
    const int jy0 = b << 7;
    int ph = 1;

    const float4* x4 = (const float4*)x;
    const float4* y4 = (const float4*)y;
    const float4* G4 = (const float4*)G;

    { // ================= tile scope (Phase A + loop) =====================
    float4 tile[32];

// One 32-col gemm pass: local cols [32*PP, 32*PP+32); fills tile[*].CMP.
#define DO_PASS(PP, CMP)                                                      \
    {                                                                         \
        f32x4 acc[4][2];                                                      \
        _Pragma("unroll")                                                     \
        for (int mi = 0; mi < 4; ++mi)                                        \
            _Pragma("unroll")                                                 \
            for (int nj = 0; nj < 2; ++nj)                                    \
                acc[mi][nj] = (f32x4){0.f, 0.f, 0.f, 0.f};                    \
        for (int kc = 0; kc < 12; ++kc) {                                     \
            __syncthreads();                                                  \
            _Pragma("unroll")                                                 \
            for (int p8 = 0; p8 < 8; ++p8) {                                  \
                const int f = (p8 << 8) + t, r = f >> 3, c4 = f & 7;          \
                xs4[(r << 3) + (c4 ^ (r & 7))] = x4[r * 96 + (kc << 3) + c4]; \
            }                                                                 \
            {                                                                 \
                const int r = t >> 3, c4 = t & 7;                             \
                float4 vy = y4[(size_t)(jy0 + (PP << 5) + r) * 96             \
                               + (kc << 3) + c4];                             \
                ushort a0,a1,a2,b0,b1,b2,g0,g1,g2,d0,d1,d2;                   \
                split3(vy.x, a0,a1,a2); split3(vy.y, b0,b1,b2);               \
                split3(vy.z, g0,g1,g2); split3(vy.w, d0,d1,d2);               \
                *(ushort4*)&ys0[r*40+(c4<<2)] = make_ushort4(a0,b0,g0,d0);    \
                *(ushort4*)&ys1[r*40+(c4<<2)] = make_ushort4(a1,b1,g1,d1);    \
                *(ushort4*)&ys2[r*40+(c4<<2)] = make_ushort4(a2,b2,g2,d2);    \
            }                                                                 \
            __syncthreads();                                                  \
            union U8 { ushort u[8]; bf16x8 v; };                              \
            _Pragma("unroll")                                                 \
            for (int mi = 0; mi < 4; ++mi) {                                  \
                const int row = (w << 6) + (mi << 4) + l15, base = row << 3;  \
                float4 xa = xs4[base + (((q << 1)    ) ^ (row & 7))];         \
                float4 xb = xs4[base + (((q << 1) + 1) ^ (row & 7))];         \
                U8 u0, u1, u2;                                                \
                split3(xa.x, u0.u[0], u1.u[0], u2.u[0]);                      \
                split3(xa.y, u0.u[1], u1.u[1], u2.u[1]);                      \
                split3(xa.z, u0.u[2], u1.u[2], u2.u[2]);                      \
                split3(xa.w, u0.u[3], u1.u[3], u2.u[3]);                      \
                split3(xb.x, u0.u[4], u1.u[4], u2.u[4]);                      \
                split3(xb.y, u0.u[5], u1.u[5], u2.u[5]);                      \
                split3(xb.z, u0.u[6], u1.u[6], u2.u[6]);                      \
                split3(xb.w, u0.u[7], u1.u[7], u2.u[7]);                      \
                _Pragma("unroll")                                             \
                for (int nj = 0; nj < 2; ++nj) {                              \
                    const int off = ((nj << 4) + l15) * 40 + (q << 3);        \
                    bf16x8 B0 = *(const bf16x8*)&ys0[off];                    \
                    bf16x8 B1 = *(const bf16x8*)&ys1[off];                    \
                    bf16x8 B2 = *(const bf16x8*)&ys2[off];                    \
                    f32x4 c = acc[mi][nj];                                    \
                    c = __builtin_amdgcn_mfma_f32_16x16x32_bf16(u0.v, B0, c, 0, 0, 0); \
                    c = __builtin_amdgcn_mfma_f32_16x16x32_bf16(u0.v, B1, c, 0, 0, 0); \
                    c = __builtin_amdgcn_mfma_f32_16x16x32_bf16(u1.v, B0, c, 0, 0, 0); \
                    c = __builtin_amdgcn_mfma_f32_16x16x32_bf16(u1.v, B1, c, 0, 0, 0); \
                    c = __builtin_amdgcn_mfma_f32_16x16x32_bf16(u0.v, B2, c, 0, 0, 0); \
                    c = __builtin_amdgcn_mfma_f32_16x16x32_bf16(u2.v, B0, c, 0, 0, 0); \
                    acc[mi][nj] = c;                                          \
                }                                                             \
            }                                                                 \
        }                                                                     \
        _Pragma("unroll")                                                     \
        for (int c4 = 0; c4 < 4; ++c4) {                                      \
            __syncthreads();                                                  \
            if (w == c4) {                                                    \
                _Pragma("unroll")                                             \
                for (int mi = 0; mi < 4; ++mi)                                \
                    _Pragma("unroll")                                         \
                    for (int nj = 0; nj < 2; ++nj)                            \
                        _Pragma("unroll")                                     \
                        for (int r = 0; r < 4; ++r)                           \
                            exb[((mi << 4) + (q << 2) + r) * 36               \
                                + (nj << 4) + l15] = 40.f * acc[mi][nj][r];   \
            }                                                                 \
            __syncthreads();                                                  \
            _Pragma("unroll")                                                 \
            for (int kk = 0; kk < 8; ++kk)                                    \
                tile[(c4 << 3) + kk].CMP = exb[(ig + (kk << 3)) * 36 + jq];   \
            _Pragma("unroll")                                                 \
            for (int cc = 0; cc < 8; ++cc) {                                  \
                const int idx = (cc << 8) + t, rr = idx >> 5, c31 = idx & 31; \
                G[(size_t)b * 32768 + (size_t)((c4 << 6) + rr) * 128          \
                  + (PP << 5) + c31] = exb[rr * 36 + c31];                    \
            }                                                                 \
        }                                                                     \
    }

    DO_PASS(0, x)
    DO_PASS(1, y)
    DO_PASS(2, z)
    DO_PASS(3, w)
#undef DO_PASS

#pragma unroll
    for (int k = 0; k < 32; ++k) PIN4(tile[k]);

    __syncthreads();                 // staging region dead; iteration begins
    su_lds[t] = su[t];               // su0 = -20*|x|^2
    __syncthreads();

    // Thread's loop columns: jq, jq+32, jq+64, jq+96 (components x,y,z,w).
    // ================= iteration 1 (log-safe, exact lse) =================
    {
        float m0=-INFINITY,m1=-INFINITY,m2=-INFINITY,m3=-INFINITY;
#pragma unroll
        for (int k = 0; k < 32; ++k) {
            const float sk = su_lds[ig + (k << 3)];
            m0=fmaxf(m0,tile[k].x+sk); m1=fmaxf(m1,tile[k].y+sk);
            m2=fmaxf(m2,tile[k].z+sk); m3=fmaxf(m3,tile[k].w+sk);
        }
        float s0=0.f,s1=0.f,s2=0.f,s3=0.f;
#pragma unroll
        for (int k = 0; k < 32; ++k) {
            const float sk = su_lds[ig + (k << 3)];
            s0+=__expf(tile[k].x+sk-m0); s1+=__expf(tile[k].y+sk-m1);
            s2+=__expf(tile[k].z+sk-m2); s3+=__expf(tile[k].w+sk-m3);
        }
        mm[ig*128+jq+ 0]=m0; ss[ig*128+jq+ 0]=s0;
        mm[ig*128+jq+32]=m1; ss[ig*128+jq+32]=s1;
        mm[ig*128+jq+64]=m2; ss[ig*128+jq+64]=s2;
        mm[ig*128+jq+96]=m3; ss[ig*128+jq+96]=s3;
        __syncthreads();
        if (t < 128) {
            float m=-INFINITY, s=0.f;
#pragma unroll
            for (int g = 0; g < 8; ++g) {
                float pmv=mm[g*128+t], psv=ss[g*128+t];
                float nm=fmaxf(m,pmv);
                s = s*__expf(m-nm) + psv*__expf(pmv-nm);
                m = nm;
            }
            Wlds[t] = LOG_B - (m + __logf(s));
        }
        __syncthreads();
    }
    // row pass (exact, two sweeps): rowmax then expsum, cross-block lse
    {
        const float Wc0=Wlds[jq], Wc1=Wlds[jq+32], Wc2=Wlds[jq+64], Wc3=Wlds[jq+96];
#pragma unroll
        for (int k = 0; k < 32; ++k) {
            const int i = ig + (k << 3);
            float a0=tile[k].x+Wc0, a1=tile[k].y+Wc1;
            float a2=tile[k].z+Wc2, a3=tile[k].w+Wc3;
            pq[i*33+jq] = fmaxf(fmaxf(a0,a1), fmaxf(a2,a3));
        }
        __syncthreads();
        {
            float R=-INFINITY;
#pragma unroll
            for (int qq = 0; qq < 32; ++qq) R = fmaxf(R, pq[t*33+qq]);
            Rlds[t] = R;
        }
        __syncthreads();
#pragma unroll
        for (int k = 0; k < 32; ++k) {
            const int i = ig + (k << 3);
            const float Rr = Rlds[i];
            float s = __expf(tile[k].x+Wc0-Rr) + __expf(tile[k].y+Wc1-Rr)
                    + __expf(tile[k].z+Wc2-Rr) + __expf(tile[k].w+Wc3-Rr);
            pq[i*33+jq] = s;
        }
        __syncthreads();
        {
            float s = 0.f;
#pragma unroll
            for (int qq = 0; qq < 32; ++qq) s += pq[t*33+qq];
            pms[(b << 8) + t] = make_float2(Rlds[t], s);
        }
    }
    if (bar_arrive(cnt, ph, t, &lastf)) {
        __threadfence();
        float m=-INFINITY, s=0.f;
        for (int p = 0; p < 256; ++p) {
            float2 v = pms[(p << 8) + t];
            float nm = fmaxf(m, v.x);
            s = s*__expf(m-nm) + v.y*__expf(v.x-nm);
            m = nm;
        }
        su[t] = LOG_A - (m + __logf(s));
        bar_release(gen, ph, t);
    }
    bar_wait(gen, ph, t); ++ph;
    su_lds[t] = su[t];
    __syncthreads();

    // ---- convergence check #1 (ref cpt_n=1): col marginal err vs b ----
    int act;
    {
        float m0=-INFINITY,m1=-INFINITY,m2=-INFINITY,m3=-INFINITY;
#pragma unroll
        for (int k = 0; k < 32; ++k) {
            const float sk = su_lds[ig + (k << 3)];
            m0=fmaxf(m0,tile[k].x+sk); m1=fmaxf(m1,tile[k].y+sk);
            m2=fmaxf(m2,tile[k].z+sk); m3=fmaxf(m3,tile[k].w+sk);
        }
        float s0=0.f,s1=0.f,s2=0.f,s3=0.f;
#pragma unroll
        for (int k = 0; k < 32; ++k) {
            const float sk = su_lds[ig + (k << 3)];
            s0+=__expf(tile[k].x+sk-m0); s1+=__expf(tile[k].y+sk-m1);
            s2+=__expf(tile[k].z+sk-m2); s3+=__expf(tile[k].w+sk-m3);
        }
        mm[ig*128+jq+ 0]=m0; ss[ig*128+jq+ 0]=s0;
        mm[ig*128+jq+32]=m1; ss[ig*128+jq+32]=s1;
        mm[ig*128+jq+64]=m2; ss[ig*128+jq+64]=s2;
        mm[ig*128+jq+96]=m3; ss[ig*128+jq+96]=s3;
        __syncthreads();
        if (t < 128) {
            float m=-INFINITY, s=0.f;
#pragma unroll
            for (int g = 0; g < 8; ++g) {
                float pmv=mm[g*128+t], psv=ss[g*128+t];
                float nm=fmaxf(m,pmv);
                s = s*__expf(m-nm) + psv*__expf(pmv-nm);
                m = nm;
            }
            errb[t] = fabsf(__expf((m + __logf(s)) + Wlds[t]) - BVAL);
        }
        __syncthreads();
        for (int n = 64; n; n >>= 1) {
            if (t < n) errb[t] = fmaxf(errb[t], errb[t + n]);
            __syncthreads();
        }
        if (t == 0) atomicMax(&colerr[0], __float_as_uint(errb[0]));
        if (bar_arrive(cnt, ph, t, &lastf)) {
            if (t == 0) {
                unsigned e = atomicMax(&colerr[0], 0u);
                active[0] = (__uint_as_float(e) > 0.005f) ? 1 : 0;
            }
            bar_release(gen, ph, t);
        }
        bar_wait(gen, ph, t); ++ph;
        act = active[0];
    }

    // ================= fast iterations 2..100 (E-reuse) =================
    if (act) {
#pragma unroll 1
        for (int tt = 2; tt <= 100; ++tt) {
            // col pass: true col max
            {
                float m0=-INFINITY,m1=-INFINITY,m2=-INFINITY,m3=-INFINITY;
#pragma unroll
                for (int k = 0; k < 32; ++k) {
                    const float sk = su_lds[ig + (k << 3)];
                    m0=fmaxf(m0,tile[k].x+sk); m1=fmaxf(m1,tile[k].y+sk);
                    m2=fmaxf(m2,tile[k].z+sk); m3=fmaxf(m3,tile[k].w+sk);
                }
                mm[ig*128+jq+ 0]=m0; mm[ig*128+jq+32]=m1;
                mm[ig*128+jq+64]=m2; mm[ig*128+jq+96]=m3;
                __syncthreads();
                if (t < 128) {
                    float m=-INFINITY;
#pragma unroll
                    for (int g = 0; g < 8; ++g) m = fmaxf(m, mm[g*128+t]);
                    Mcol[t] = m;
                }
                __syncthreads();
            }
            float4 E[32];
            {
                const float Mc0=Mcol[jq], Mc1=Mcol[jq+32], Mc2=Mcol[jq+64], Mc3=Mcol[jq+96];
                float s0=0.f,s1=0.f,s2=0.f,s3=0.f;
#pragma unroll
                for (int k = 0; k < 32; ++k) {
                    const float sk = su_lds[ig + (k << 3)];
                    E[k].x=__expf(tile[k].x+sk-Mc0); s0+=E[k].x;
                    E[k].y=__expf(tile[k].y+sk-Mc1); s1+=E[k].y;
                    E[k].z=__expf(tile[k].z+sk-Mc2); s2+=E[k].z;
                    E[k].w=__expf(tile[k].w+sk-Mc3); s3+=E[k].w;
                }
                ss[ig*128+jq+ 0]=s0; ss[ig*128+jq+32]=s1;
                ss[ig*128+jq+64]=s2; ss[ig*128+jq+96]=s3;
                __syncthreads();
                if (t < 128) {
                    float ssum = 0.f;
#pragma unroll
                    for (int g = 0; g < 8; ++g) ssum += ss[g*128+t];
                    Wlds[t] = LOG_B - (Mcol[t] + __logf(ssum));
                    ecol[t] = 1.0f / ssum;
                }
                __syncthreads();
            }
            // row pass: partial = dot(E_rowslice, 1/S)
            {
                const float e0=ecol[jq], e1=ecol[jq+32], e2=ecol[jq+64], e3=ecol[jq+96];
#pragma unroll
                for (int k = 0; k < 32; ++k) {
                    const int i = ig + (k << 3);
                    pq[i*33+jq] = E[k].x*e0 + E[k].y*e1 + E[k].z*e2 + E[k].w*e3;
                }
                __syncthreads();
                float s = 0.f;
#pragma unroll
                for (int qq = 0; qq < 32; ++qq) s += pq[t*33+qq];
                prow[(b << 8) + t] = s;
            }
            if (bar_arrive(cnt, ph, t, &lastf)) {
                __threadfence();
                float tot = 0.f;
                for (int p = 0; p < 256; ++p) tot += prow[(p << 8) + t];
                su[t] = (LOG_A - LOG_B) + su_lds[t] - __logf(tot);
                bar_release(gen, ph, t);
            }
            bar_wait(gen, ph, t); ++ph;
            su_lds[t] = su[t];
            __syncthreads();

            if (tt == 51) {
                // convergence check #2 (ref cpt_n=51)
                float m0=-INFINITY,m1=-INFINITY,m2=-INFINITY,m3=-INFINITY;
#pragma unroll
                for (int k = 0; k < 32; ++k) {
                    const float sk = su_lds[ig + (k << 3)];
                    m0=fmaxf(m0,tile[k].x+sk); m1=fmaxf(m1,tile[k].y+sk);
                    m2=fmaxf(m2,tile[k].z+sk); m3=fmaxf(m3,tile[k].w+sk);
                }
                float s0=0.f,s1=0.f,s2=0.f,s3=0.f;
#pragma unroll
                for (int k = 0; k < 32; ++k) {
                    const float sk = su_lds[ig + (k << 3)];
                    s0+=__expf(tile[k].x+sk-m0); s1+=__expf(tile[k].y+sk-m1);
                    s2+=__expf(tile[k].z+sk-m2); s3+=__expf(tile[k].w+sk-m3);
                }
                mm[ig*128+jq+ 0]=m0; ss[ig*128+jq+ 0]=s0;
                mm[ig*128+jq+32]=m1; ss[ig*128+jq+32]=s1;
                mm[ig*128+jq+64]=m2; ss[ig*128+jq+64]=s2;
                mm[ig*128+jq+96]=m3; ss[ig*128+jq+96]=s3;
                __syncthreads();
                if (t < 128) {
                    float m=-INFINITY, s=0.f;
#pragma unroll
                    for (int g = 0; g < 8; ++g) {
                        float pmv=mm[g*128+t], psv=ss[g*128+t];
                        float nm=fmaxf(m,pmv);
                        s = s*__expf(m-nm) + psv*__expf(pmv-nm);
                        m = nm;
                    }
                    errb[t] = fabsf(__expf((m + __logf(s)) + Wlds[t]) - BVAL);
                }
                __syncthreads();
                for (int n = 64; n; n >>= 1) {
                    if (t < n) errb[t] = fmaxf(errb[t], errb[t + n]);
                    __syncthreads();
                }
                if (t == 0) atomicMax(&colerr[1], __float_as_uint(errb[0]));
                if (bar_arrive(cnt, ph, t, &lastf)) {
                    if (t == 0) {
                        unsigned e = atomicMax(&colerr[1], 0u);
                        active[0] = (__uint_as_float(e) > 0.005f) ? 1 : 0;
                    }
                    bar_release(gen, ph, t);
                }
                bar_wait(gen, ph, t); ++ph;
                if (active[0] == 0) break;
            }
        }
    }
    }   // ---- tile dead here (scope closed) ----

    // ================= Phase D: fused finalize (G reloaded, R22 map) ======
    nxl[t] = nx[t];
    if (t < 128) nyl[t] = ny[jy0 + t];
    __syncthreads();

    const float Wc0 = Wlds[c0+0], Wc1 = Wlds[c0+1], Wc2 = Wlds[c0+2], Wc3 = Wlds[c0+3];
    const float ny0 = nyl[c0+0], ny1 = nyl[c0+1], ny2 = nyl[c0+2], ny3 = nyl[c0+3];
    float accl = 0.f;
#pragma unroll 4
    for (int k = 0; k < 32; ++k) {
        const int i = ig + (k << 3);
        float4 g = G4[((size_t)b << 13) + (i << 5) + jq];   // L2/L3-hot reload
        const float si = su_lds[i], nxi = nxl[i];
        float v0 = __expf(g.x + si + Wc0);
        float v1 = __expf(g.y + si + Wc1);
        float v2 = __expf(g.z + si + Wc2);
        float v3 = __expf(g.w + si + Wc3);
        float* o = out + 1 + (size_t)i * 32768 + jy0 + c0;
        __builtin_nontemporal_store(v0, o + 0);
        __builtin_nontemporal_store(v1, o + 1);
        __builtin_nontemporal_store(v2, o + 2);
        __builtin_nontemporal_store(v3, o + 3);
        accl += v0 * (nxi + ny0 - 0.05f * g.x) +
                v1 * (nxi + ny1 - 0.05f * g.y) +
                v2 * (nxi + ny2 - 0.05f * g.z) +
                v3 * (nxi + ny3 - 0.05f * g.w);
    }
    for (int off = 32; off; off >>= 1) accl += __shfl_down(accl, off);
    if (ln == 0) errb[w] = accl;
    __syncthreads();
    if (t == 0) atomicAdd(out, errb[0] + errb[1] + errb[2] + errb[3]);
}

// ---------------------------------------------------------------- host ------
extern "C" void kernel_launch(void* const* d_in, const int* in_sizes, int n_in,
                              void* d_out, int out_size, void* d_ws, size_t ws_size,
                              hipStream_t stream)
{
    const float* x = (const float*)d_in[0];   // [256, 384]
    const float* y = (const float*)d_in[1];   // [32768, 384]
    float* out = (float*)d_out;               // [1 + 256*32768]

    float* ws   = (float*)d_ws;
    float* G    = ws;                              // 8388608 (tiled [256][256][128])
    float* su   = G + 8388608;                     // 256
    float* nx   = su + 256;                        // 256
    float* ny   = nx + 256;                        // 32768
    float2* pms = (float2*)(ny + 32768);           // 65536 float2
    float* prow = (float*)(pms + 65536);           // 65536
    unsigned* colerr = (unsigned*)(prow + 65536);  // 2
    int* active   = (int*)(colerr + 2);            // 1
    int* counters = active + 1;                    // 4096 (barrier slots + gen)
    int* gen      = counters + 3000;

    init_k<<<8257, 256, 0, stream>>>(x, y, nx, ny, su, colerr, active, counters, out);
    fused_k<<<256, 256, 0, stream>>>(x, y, G, su, nx, ny, pms, prow,
                                     counters, gen, colerr, active, out);
}